// Round 1
// baseline (1658.682 us; speedup 1.0000x reference)
//
#include <hip/hip_runtime.h>

// NeuralODE: B=1024, D=64, F=8, H=256, 196 substeps x 6 dopri5 stages.
// R10: barrier-minimal 4-wave symmetric design. 64 blocks x 256 threads
// (4 waves, 1/SIMD, __launch_bounds__(256,1) -> 512-VGPR budget).
// R9 post-mortem: latency-bound (MfmaUtil 5%, VALUBusy 14%); stage path =
// 3 barriers + 3 LDS round-trips; GEMM2's 4-way K-split + red[] reduce
// spent a barrier + round-trip to spread MFMAs that were 5% utilized.
// R10 structure (2 barriers, 2 round-trips, no reduce):
//  - Wave wv owns GEMM1 N-tiles wv*4+t (t=0..3): B-frags in regs
//    (24 half8 hi+lo), 3 A-reads, 24 MFMAs, 16 tanh -> h writes.
//  - Wave wv owns GEMM2 N-tile wv with FULL K=256: 16 half8 B-frags,
//    8 A-reads, 16 MFMAs. D-layout [row=(l>>4)*4+reg][col=l&15] == state
//    layout (cols wv*16+lm), so k_s lands directly in state regs: red[]
//    reduce + its barrier are gone. All 4 waves fully symmetric.
// Numerics identical to R9: W1/W2 hi+lo 2-term split, z-residual dropped,
// fp32 state + dopri5 combine (absmax floor ~0.0156).
// A-frag LDS planes [k>>3][m][k&7], stride 144 halves (288B), b128 reads
// 8-access/bank balanced. MFMA layouts (HW-verified R7/R8):
//   A[m=l&15][k=(l>>4)*8+j], B[k=(l>>4)*8+j][n=l&15],
//   D[row=(l>>4)*4+reg][col=l&15].

typedef _Float16 half8 __attribute__((ext_vector_type(8)));
typedef float f32x4 __attribute__((ext_vector_type(4)));

#define MFMA16(a, b, c) __builtin_amdgcn_mfma_f32_16x16x32_f16((a), (b), (c), 0, 0, 0)

__device__ __forceinline__ float fast_tanh(float x) {
    float e = __expf(2.0f * x);
    return 1.0f - 2.0f / (e + 1.0f);   // saturates correctly, ~1e-6 abs err
}

__global__ __launch_bounds__(256, 1)
void node_kernel(const float* __restrict__ x0,
                 const float* __restrict__ t_eval,
                 const float* __restrict__ t_u,
                 const float* __restrict__ u_batch,
                 const float* __restrict__ W1,
                 const float* __restrict__ b1,
                 const float* __restrict__ W2,
                 const float* __restrict__ b2,
                 float* __restrict__ out)
{
    __shared__ __align__(16) _Float16 zAh[12 * 144];   // z hi, K=96 (72+pad)
    __shared__ __align__(16) _Float16 hAh[32 * 144];   // h hi, K=256
    __shared__ __align__(16) float ush[6][16][8];      // interp u per stage/row

    const int tid = threadIdx.x;
    const int wv  = tid >> 6;        // wave 0..3
    const int l   = tid & 63;
    const int lm  = l & 15;
    const int lq  = l >> 4;
    const int blk = blockIdx.x;

    // --- zero z K-pad planes (k=72..95 -> planes 9..11): 216 dwords ---
    if (tid < 216) *(uint32_t*)&zAh[9 * 144 + tid * 2] = 0u;

    // --- GEMM1 B-frags: wave owns N-tiles wv*4+t, split hi/lo ---
    half8 b1h[4][3], b1l[4][3];
    float b1b[4];
#pragma unroll
    for (int t = 0; t < 4; ++t) {
        const int n1 = (wv * 4 + t) * 16 + lm;
        b1b[t] = b1[n1];
#pragma unroll
        for (int c = 0; c < 3; ++c) {
#pragma unroll
            for (int j = 0; j < 8; ++j) {
                const int k = c * 32 + lq * 8 + j;
                const float v = (k < 72) ? W1[k * 256 + n1] : 0.0f;
                const _Float16 hi = (_Float16)v;
                b1h[t][c][j] = hi;
                b1l[t][c][j] = (_Float16)(v - (float)hi);
            }
        }
    }

    // --- GEMM2 B-frags: wave owns N-tile wv, FULL K=256 ---
    const int n2 = wv * 16 + lm;
    half8 b2h[8], b2l[8];
#pragma unroll
    for (int cc = 0; cc < 8; ++cc) {
#pragma unroll
        for (int j = 0; j < 8; ++j) {
            const int k = cc * 32 + lq * 8 + j;
            const float v = W2[k * 64 + n2];
            const _Float16 hi = (_Float16)v;
            b2h[cc][j] = hi;
            b2l[cc][j] = (_Float16)(v - (float)hi);
        }
    }
    const float b2b = b2[n2];

    // --- ODE state: wave wv owns cols wv*16+lm, rows lq*4+r ---
    float xr[4];
    float kfr[5][4];
#pragma unroll
    for (int r = 0; r < 4; ++r) {
        const int gr = blk * 16 + lq * 4 + r;
        xr[r] = x0[gr * 64 + n2];
        out[gr * 3200 + n2] = xr[r];      // t_eval[0]
    }
    __syncthreads();   // pad zeros visible

#pragma unroll 1
    for (int step = 0; step < 196; ++step) {
        const int n = step >> 2;
        const int m = step & 3;
        const float te0 = t_eval[n];
        const float dtc = t_eval[n + 1] - te0;
        const float t   = te0 + dtc * (0.25f * (float)m);
        const float dt  = dtc * 0.25f;

        // --- u prefetch+interp: 768 slots over 256 threads (3 rounds) ---
#pragma unroll
        for (int base = 0; base < 768; base += 256) {
            const int idx = base + tid;
            const int s   = idx >> 7;           // wave-uniform (128 = 2 waves)
            const int rem = idx & 127;
            const int mr  = rem >> 3, f = rem & 7;
            float cs;
            switch (s) {
                case 0: cs = 0.0f; break;
                case 1: cs = 1.0f / 5.0f; break;
                case 2: cs = 3.0f / 10.0f; break;
                case 3: cs = 4.0f / 5.0f; break;
                case 4: cs = 8.0f / 9.0f; break;
                default: cs = 1.0f; break;
            }
            const float tsv = t + dt * cs;
            int iu = (int)(tsv * 127.0f);       // == searchsorted-1
            iu = iu < 0 ? 0 : (iu > 126 ? 126 : iu);
            const float ta = t_u[iu];
            const float tb = t_u[iu + 1];
            const float wt = (tsv - ta) / (tb - ta);
            const float* ub = &u_batch[(blk * 16 + mr) * 1024 + iu * 8 + f];
            const float u0v = ub[0];
            const float u1v = ub[8];
            ush[s][mr][f] = fmaf(wt, u1v - u0v, u0v);
        }
        __syncthreads();   // B0: ush ready

#pragma unroll
        for (int s = 0; s < 6; ++s) {
            // --- every wave publishes z x-part for its own cols (hi only) ---
#pragma unroll
            for (int r = 0; r < 4; ++r) {
                float v;
                if (s == 0)      v = xr[r];
                else if (s == 1) v = fmaf(dt, kfr[0][r] * (1.0f/5.0f), xr[r]);
                else if (s == 2) v = fmaf(dt, fmaf(3.0f/40.0f, kfr[0][r], (9.0f/40.0f)*kfr[1][r]), xr[r]);
                else if (s == 3) v = fmaf(dt, (44.0f/45.0f)*kfr[0][r] + (-56.0f/15.0f)*kfr[1][r]
                                             + (32.0f/9.0f)*kfr[2][r], xr[r]);
                else if (s == 4) v = fmaf(dt, (19372.0f/6561.0f)*kfr[0][r] + (-25360.0f/2187.0f)*kfr[1][r]
                                             + (64448.0f/6561.0f)*kfr[2][r] + (-212.0f/729.0f)*kfr[3][r], xr[r]);
                else             v = fmaf(dt, (9017.0f/3168.0f)*kfr[0][r] + (-355.0f/33.0f)*kfr[1][r]
                                             + (46732.0f/5247.0f)*kfr[2][r] + (49.0f/176.0f)*kfr[3][r]
                                             + (-5103.0f/18656.0f)*kfr[4][r], xr[r]);
                zAh[(n2 >> 3) * 144 + (lq * 4 + r) * 8 + (n2 & 7)] = (_Float16)v;
            }
            // --- wave 1: z u-part (plane 8), dword-packed ---
            if (wv == 1) {
                const int mm = l >> 2;
                const int jj = (l & 3) * 2;
                const _Float16 u0h = (_Float16)ush[s][mm][jj];
                const _Float16 u1h = (_Float16)ush[s][mm][jj + 1];
                uint32_t pk = (uint32_t)*(const uint16_t*)&u0h
                            | ((uint32_t)*(const uint16_t*)&u1h << 16);
                *(uint32_t*)&zAh[8 * 144 + mm * 8 + jj] = pk;
            }
            __syncthreads();   // B1: z ready

            // --- GEMM1: 3 A-reads, 4 N-tiles, 2-term split, 24 MFMAs ---
            half8 az[3];
#pragma unroll
            for (int c = 0; c < 3; ++c)
                az[c] = *(const half8*)&zAh[(c * 4 + lq) * 144 + lm * 8];
#pragma unroll
            for (int t = 0; t < 4; ++t) {
                f32x4 aHH = {0.f, 0.f, 0.f, 0.f};
                f32x4 aHL = {0.f, 0.f, 0.f, 0.f};
#pragma unroll
                for (int c = 0; c < 3; ++c) {
                    aHH = MFMA16(az[c], b1h[t][c], aHH);
                    aHL = MFMA16(az[c], b1l[t][c], aHL);
                }
                const int kqb = (wv * 4 + t) * 2 + (lm >> 3);   // h-col>>3 plane
#pragma unroll
                for (int r = 0; r < 4; ++r) {
                    const float hv = fast_tanh(aHH[r] + aHL[r] + b1b[t]);
                    hAh[kqb * 144 + (lq * 4 + r) * 8 + (lm & 7)] = (_Float16)hv;
                }
            }
            __syncthreads();   // B2: h ready

            // --- GEMM2: full K=256, 8 A-reads, 16 MFMAs; D-layout == state
            //     layout -> k_s directly in regs, no reduce, no barrier ---
            f32x4 aP = {0.f, 0.f, 0.f, 0.f};
            f32x4 aQ = {0.f, 0.f, 0.f, 0.f};
#pragma unroll
            for (int cc = 0; cc < 8; ++cc) {
                const half8 ah = *(const half8*)&hAh[(cc * 4 + lq) * 144 + lm * 8];
                aP = MFMA16(ah, b2h[cc], aP);
                aQ = MFMA16(ah, b2l[cc], aQ);
            }
            if (s < 5) {
#pragma unroll
                for (int r = 0; r < 4; ++r)
                    kfr[s][r] = (aP[r] + aQ[r]) + b2b;
            } else {
#pragma unroll
                for (int r = 0; r < 4; ++r) {
                    const float k6 = (aP[r] + aQ[r]) + b2b;
                    xr[r] = fmaf(dt, (35.0f/384.0f)*kfr[0][r] + (500.0f/1113.0f)*kfr[2][r]
                                    + (125.0f/192.0f)*kfr[3][r] + (-2187.0f/6784.0f)*kfr[4][r]
                                    + (11.0f/84.0f)*k6, xr[r]);
                }
            }
        }

        // --- output every 4th substep ---
        if (m == 3) {
#pragma unroll
            for (int r = 0; r < 4; ++r)
                out[(blk * 16 + lq * 4 + r) * 3200 + (n + 1) * 64 + n2] = xr[r];
        }
    }
}

extern "C" void kernel_launch(void* const* d_in, const int* in_sizes, int n_in,
                              void* d_out, int out_size, void* d_ws, size_t ws_size,
                              hipStream_t stream) {
    const float* x0      = (const float*)d_in[0];
    const float* t_eval  = (const float*)d_in[1];
    const float* t_u     = (const float*)d_in[2];
    const float* u_batch = (const float*)d_in[3];
    const float* W1      = (const float*)d_in[4];
    const float* b1      = (const float*)d_in[5];
    const float* W2      = (const float*)d_in[6];
    const float* b2      = (const float*)d_in[7];
    float* out = (float*)d_out;

    node_kernel<<<dim3(64), dim3(256), 0, stream>>>(
        x0, t_eval, t_u, u_batch, W1, b1, W2, b2, out);
}

// Round 2
// 1200.943 us; speedup vs baseline: 1.3812x; 1.3812x over previous
//
#include <hip/hip_runtime.h>

// NeuralODE: B=1024, D=64, F=8, H=256, 196 substeps x 6 dopri5 stages.
// R11: co-resident-block latency hiding. 512 blocks x 256 threads, 2 rows
// per block -> 2 independent blocks per CU (launch_bounds(256,2)).
// R9/R10 post-mortem: R9 (16w, 3 barriers) == R10 (4w, 2 barriers) ->
// intra-block TLP hides nothing (all waves wait on the same LDS turnaround);
// stage cost = ~650cyc issue + ~2x exposed write->barrier->read + chain
// latency. Only an INDEPENDENT co-resident block can fill those stalls.
// Changes vs R10:
//  - grid 64x16rows -> 512x2rows (2 blocks/CU). M=16 tile padding rows are
//    zero-initialized in LDS once (never written again) -> exact zeros, no
//    NaN; all row-scaled issue (tanh/combine/z-publish/h-write) pruned to
//    regs r=0,1 (per-wave tanh issue halves).
//  - GEMM2 W2-lo term dropped (adds ~2.4e-4 to k vs existing ~7e-4
//    h-rounding error): 16->8 MFMAs, 2 dep-chains of 4.
//  - tanh: 2*log2(e) folded into W1/b1 staging; h = 1 - 2*rcp(exp2(y)+1)
//    via __builtin_amdgcn_exp2f/rcpf (kills the fp32 divide sequence).
// MFMA layouts (HW-verified R7/R8): A[m=l&15][k=(l>>4)*8+j],
//   B[k=(l>>4)*8+j][n=l&15], D[row=(l>>4)*4+reg][col=l&15].
// A-frag LDS planes [k>>3][m][k&7], stride 144 halves (288B).

typedef _Float16 half8 __attribute__((ext_vector_type(8)));
typedef float f32x4 __attribute__((ext_vector_type(4)));

#define MFMA16(a, b, c) __builtin_amdgcn_mfma_f32_16x16x32_f16((a), (b), (c), 0, 0, 0)

__global__ __launch_bounds__(256, 2)
void node_kernel(const float* __restrict__ x0,
                 const float* __restrict__ t_eval,
                 const float* __restrict__ t_u,
                 const float* __restrict__ u_batch,
                 const float* __restrict__ W1,
                 const float* __restrict__ b1,
                 const float* __restrict__ W2,
                 const float* __restrict__ b2,
                 float* __restrict__ out)
{
    __shared__ __align__(16) _Float16 zAh[12 * 144];   // z hi, K=96 (72+pad)
    __shared__ __align__(16) _Float16 hAh[32 * 144];   // h hi, K=256
    __shared__ __align__(16) float ush[6][2][8];       // interp u per stage/row

    const int tid = threadIdx.x;
    const int wv  = tid >> 6;        // wave 0..3
    const int l   = tid & 63;
    const int lm  = l & 15;
    const int lq  = l >> 4;
    const int blk = blockIdx.x;

    const float C2L = 2.8853900817779268f;   // 2*log2(e)

    // --- zero ALL of zAh/hAh once: padding rows/planes stay 0 forever ---
    for (int i = tid; i < (12 * 144) / 2; i += 256) ((uint32_t*)zAh)[i] = 0u;
    for (int i = tid; i < (32 * 144) / 2; i += 256) ((uint32_t*)hAh)[i] = 0u;

    // --- GEMM1 B-frags: wave owns N-tiles wv*4+t, hi/lo, prescaled 2log2e ---
    half8 b1h[4][3], b1l[4][3];
    float b1b[4];
#pragma unroll
    for (int t = 0; t < 4; ++t) {
        const int n1 = (wv * 4 + t) * 16 + lm;
        b1b[t] = b1[n1] * C2L;
#pragma unroll
        for (int c = 0; c < 3; ++c) {
#pragma unroll
            for (int j = 0; j < 8; ++j) {
                const int k = c * 32 + lq * 8 + j;
                const float v = (k < 72) ? W1[k * 256 + n1] * C2L : 0.0f;
                const _Float16 hi = (_Float16)v;
                b1h[t][c][j] = hi;
                b1l[t][c][j] = (_Float16)(v - (float)hi);
            }
        }
    }

    // --- GEMM2 B-frags: wave owns N-tile wv, FULL K=256, hi term only ---
    const int n2 = wv * 16 + lm;
    half8 b2h[8];
#pragma unroll
    for (int cc = 0; cc < 8; ++cc) {
#pragma unroll
        for (int j = 0; j < 8; ++j) {
            const int k = cc * 32 + lq * 8 + j;
            b2h[cc][j] = (_Float16)W2[k * 64 + n2];
        }
    }
    const float b2b = b2[n2];

    // --- ODE state: 2 valid rows (tile rows 0,1 <-> lq==0, regs 0,1).
    //     All lanes carry copies; only lq==0 lanes are ever published. ---
    float xr[2];
    float kfr[5][2];
#pragma unroll
    for (int r = 0; r < 2; ++r) {
        const int gr = blk * 2 + r;
        xr[r] = x0[gr * 64 + n2];
        if (lq == 0) out[gr * 3200 + n2] = xr[r];      // t_eval[0]
    }
    __syncthreads();   // zero-init visible

#pragma unroll 1
    for (int step = 0; step < 196; ++step) {
        const int n = step >> 2;
        const int m = step & 3;
        const float te0 = t_eval[n];
        const float dtc = t_eval[n + 1] - te0;
        const float t   = te0 + dtc * (0.25f * (float)m);
        const float dt  = dtc * 0.25f;

        // --- u prefetch+interp: 96 slots (6 stages x 2 rows x 8 feats) ---
        if (tid < 96) {
            const int s   = tid >> 4;
            const int rem = tid & 15;
            const int mr  = rem >> 3, f = rem & 7;
            float cs;
            switch (s) {
                case 0: cs = 0.0f; break;
                case 1: cs = 1.0f / 5.0f; break;
                case 2: cs = 3.0f / 10.0f; break;
                case 3: cs = 4.0f / 5.0f; break;
                case 4: cs = 8.0f / 9.0f; break;
                default: cs = 1.0f; break;
            }
            const float tsv = t + dt * cs;
            int iu = (int)(tsv * 127.0f);       // == searchsorted-1
            iu = iu < 0 ? 0 : (iu > 126 ? 126 : iu);
            const float ta = t_u[iu];
            const float tb = t_u[iu + 1];
            const float wt = (tsv - ta) / (tb - ta);
            const float* ub = &u_batch[(blk * 2 + mr) * 1024 + iu * 8 + f];
            const float u0v = ub[0];
            const float u1v = ub[8];
            ush[s][mr][f] = fmaf(wt, u1v - u0v, u0v);
        }
        __syncthreads();   // B0: ush ready

#pragma unroll
        for (int s = 0; s < 6; ++s) {
            // --- z x-part for rows 0,1 (combine in all lanes, lq==0 writes) ---
            float zv[2];
#pragma unroll
            for (int r = 0; r < 2; ++r) {
                float v;
                if (s == 0)      v = xr[r];
                else if (s == 1) v = fmaf(dt, kfr[0][r] * (1.0f/5.0f), xr[r]);
                else if (s == 2) v = fmaf(dt, fmaf(3.0f/40.0f, kfr[0][r], (9.0f/40.0f)*kfr[1][r]), xr[r]);
                else if (s == 3) v = fmaf(dt, (44.0f/45.0f)*kfr[0][r] + (-56.0f/15.0f)*kfr[1][r]
                                             + (32.0f/9.0f)*kfr[2][r], xr[r]);
                else if (s == 4) v = fmaf(dt, (19372.0f/6561.0f)*kfr[0][r] + (-25360.0f/2187.0f)*kfr[1][r]
                                             + (64448.0f/6561.0f)*kfr[2][r] + (-212.0f/729.0f)*kfr[3][r], xr[r]);
                else             v = fmaf(dt, (9017.0f/3168.0f)*kfr[0][r] + (-355.0f/33.0f)*kfr[1][r]
                                             + (46732.0f/5247.0f)*kfr[2][r] + (49.0f/176.0f)*kfr[3][r]
                                             + (-5103.0f/18656.0f)*kfr[4][r], xr[r]);
                zv[r] = v;
            }
            if (lq == 0) {
#pragma unroll
                for (int r = 0; r < 2; ++r)
                    zAh[(n2 >> 3) * 144 + r * 8 + (n2 & 7)] = (_Float16)zv[r];
            }
            // --- wave 1, lanes 0-7: z u-part rows 0,1 (plane 8), packed ---
            if (wv == 1 && l < 8) {
                const int mm = l >> 2;              // row 0,1
                const int jj = (l & 3) * 2;
                const _Float16 u0h = (_Float16)ush[s][mm][jj];
                const _Float16 u1h = (_Float16)ush[s][mm][jj + 1];
                uint32_t pk = (uint32_t)*(const uint16_t*)&u0h
                            | ((uint32_t)*(const uint16_t*)&u1h << 16);
                *(uint32_t*)&zAh[8 * 144 + mm * 8 + jj] = pk;
            }
            __syncthreads();   // B1: z ready

            // --- GEMM1: 3 A-reads, 4 N-tiles, 2-term, 24 MFMAs ---
            half8 az[3];
#pragma unroll
            for (int c = 0; c < 3; ++c)
                az[c] = *(const half8*)&zAh[(c * 4 + lq) * 144 + lm * 8];
#pragma unroll
            for (int t = 0; t < 4; ++t) {
                f32x4 aHH = {0.f, 0.f, 0.f, 0.f};
                f32x4 aHL = {0.f, 0.f, 0.f, 0.f};
#pragma unroll
                for (int c = 0; c < 3; ++c) {
                    aHH = MFMA16(az[c], b1h[t][c], aHH);
                    aHL = MFMA16(az[c], b1l[t][c], aHL);
                }
                const int kqb = (wv * 4 + t) * 2 + (lm >> 3);   // h-col>>3 plane
                // tanh only on valid regs r=0,1 (rows 0,1 live in lq==0)
#pragma unroll
                for (int r = 0; r < 2; ++r) {
                    const float y = aHH[r] + aHL[r] + b1b[t];       // 2log2e * (zW1+b1)
                    const float e = __builtin_amdgcn_exp2f(y);
                    const float hv = fmaf(-2.0f, __builtin_amdgcn_rcpf(e + 1.0f), 1.0f);
                    if (lq == 0)
                        hAh[kqb * 144 + r * 8 + (lm & 7)] = (_Float16)hv;
                }
            }
            __syncthreads();   // B2: h ready

            // --- GEMM2: full K=256, hi only, 8 MFMAs in 2 dep-chains of 4 ---
            f32x4 aP = {0.f, 0.f, 0.f, 0.f};
            f32x4 aR = {0.f, 0.f, 0.f, 0.f};
#pragma unroll
            for (int cc = 0; cc < 8; cc += 2) {
                const half8 ah0 = *(const half8*)&hAh[((cc    ) * 4 + lq) * 144 + lm * 8];
                const half8 ah1 = *(const half8*)&hAh[((cc + 1) * 4 + lq) * 144 + lm * 8];
                aP = MFMA16(ah0, b2h[cc    ], aP);
                aR = MFMA16(ah1, b2h[cc + 1], aR);
            }
            if (s < 5) {
#pragma unroll
                for (int r = 0; r < 2; ++r)
                    kfr[s][r] = (aP[r] + aR[r]) + b2b;
            } else {
#pragma unroll
                for (int r = 0; r < 2; ++r) {
                    const float k6 = (aP[r] + aR[r]) + b2b;
                    xr[r] = fmaf(dt, (35.0f/384.0f)*kfr[0][r] + (500.0f/1113.0f)*kfr[2][r]
                                    + (125.0f/192.0f)*kfr[3][r] + (-2187.0f/6784.0f)*kfr[4][r]
                                    + (11.0f/84.0f)*k6, xr[r]);
                }
            }
        }

        // --- output every 4th substep ---
        if (m == 3 && lq == 0) {
#pragma unroll
            for (int r = 0; r < 2; ++r)
                out[(blk * 2 + r) * 3200 + (n + 1) * 64 + n2] = xr[r];
        }
    }
}

extern "C" void kernel_launch(void* const* d_in, const int* in_sizes, int n_in,
                              void* d_out, int out_size, void* d_ws, size_t ws_size,
                              hipStream_t stream) {
    const float* x0      = (const float*)d_in[0];
    const float* t_eval  = (const float*)d_in[1];
    const float* t_u     = (const float*)d_in[2];
    const float* u_batch = (const float*)d_in[3];
    const float* W1      = (const float*)d_in[4];
    const float* b1      = (const float*)d_in[5];
    const float* W2      = (const float*)d_in[6];
    const float* b2      = (const float*)d_in[7];
    float* out = (float*)d_out;

    node_kernel<<<dim3(512), dim3(256), 0, stream>>>(
        x0, t_eval, t_u, u_batch, W1, b1, W2, b2, out);
}